// Round 3
// baseline (920.769 us; speedup 1.0000x reference)
//
#include <hip/hip_runtime.h>
#include <math.h>

// Problem constants (from reference)
#define B_TOT     16384
#define NUM_CARDS 64
#define NUM_WORDS 50
#define LEN_EMB   128
#define ROWS_PER_WAVE   4
#define WAVES_PER_BLOCK 4
#define ROWS_PER_BLOCK  (ROWS_PER_WAVE * WAVES_PER_BLOCK)  // 16
#define NSLOT 25   // 2 words per slot (one per half-wave)

// ---- setup: transpose W [e][d] -> Wt [d][e] in ws (64 KB), so the matvec
// can read W coalesced (the R0/R1 row-per-lane reads were 512B-strided:
// 64 cache lines per load instruction = L1/TA serialization ~109us/CU). ----
__global__ __launch_bounds__(256) void transpose_W(const float* __restrict__ W,
                                                   float* __restrict__ Wt) {
  int tid = blockIdx.x * 256 + threadIdx.x;  // 64 blocks * 256 = 16384 elems
  int d = tid >> 7, e = tid & 127;
  Wt[tid] = W[e * 128 + d];  // Wt[d*128+e]; writes coalesced
}

// One wave handles 4 batch rows (W reads amortized 4x, 4-way prologue ILP).
// Lane l (l=lane&31) owns output features e=4l..4l+3 as a float4; the leader
// vector never leaves registers between matvec and cosine.
__global__ __launch_bounds__(256, 4) void imaginarium_kernel(
    const float* __restrict__ img,   // [B, 64, 128]
    const float* __restrict__ txt,   // [B, 50, 128]
    const float* __restrict__ y,     // [B, 64]
    const float* __restrict__ Wt,    // [128, 128] transposed [d][e]
    const float* __restrict__ bias,  // [128]
    float* __restrict__ out)         // [B, 50]
{
  const int wid  = threadIdx.x >> 6;
  const int lane = threadIdx.x & 63;
  const int l    = lane & 31;   // lane within half-wave
  const int h    = lane >> 5;   // which half
  const int b0   = (blockIdx.x * WAVES_PER_BLOCK + wid) * ROWS_PER_WAVE;

  __shared__ float s_emb[WAVES_PER_BLOCK][ROWS_PER_WAVE][LEN_EMB];
  __shared__ float s_logit[WAVES_PER_BLOCK][ROWS_PER_WAVE][64];  // 50 used

  // ---- txt bases + depth-2 prefetch issued FIRST: 8 HBM loads fly while the
  //      prologue (argmax/gather/matvec) runs ----
  const float4* txt4[ROWS_PER_WAVE];
  #pragma unroll
  for (int r = 0; r < ROWS_PER_WAVE; ++r)
    txt4[r] = (const float4*)(txt + (size_t)(b0 + r) * NUM_WORDS * LEN_EMB);
  float4 t[2][ROWS_PER_WAVE];
  #pragma unroll
  for (int s = 0; s < 2; ++s)
    #pragma unroll
    for (int r = 0; r < ROWS_PER_WAVE; ++r)
      t[s][r] = txt4[r][(size_t)(2 * s + h) * 32 + l];

  // ---- argmax per row (first occurrence wins), 4 chains interleaved ----
  float v[ROWS_PER_WAVE];
  int   vi[ROWS_PER_WAVE];
  #pragma unroll
  for (int r = 0; r < ROWS_PER_WAVE; ++r) {
    v[r]  = y[(size_t)(b0 + r) * NUM_CARDS + lane];
    vi[r] = lane;
  }
  #pragma unroll
  for (int m = 1; m < 64; m <<= 1) {
    #pragma unroll
    for (int r = 0; r < ROWS_PER_WAVE; ++r) {
      float ov = __shfl_xor(v[r],  m, 64);
      int   oi = __shfl_xor(vi[r], m, 64);
      if (ov > v[r] || (ov == v[r] && oi < vi[r])) { v[r] = ov; vi[r] = oi; }
    }
  }

  // ---- gather leader embeddings (contiguous 512B rows) into LDS ----
  #pragma unroll
  for (int r = 0; r < ROWS_PER_WAVE; ++r) {
    const float2* embp =
        (const float2*)(img + ((size_t)(b0 + r) * NUM_CARDS + vi[r]) * LEN_EMB);
    float2 e2 = embp[lane];
    s_emb[wid][r][2 * lane]     = e2.x;
    s_emb[wid][r][2 * lane + 1] = e2.y;
  }
  // same-wave LDS write->read: compiler inserts lgkmcnt; no barrier needed.

  // ---- matvec, coalesced: half h covers d = h*64 + i; per iter the wave
  //      loads 2 full contiguous Wt rows (1KB, minimum line count) ----
  float4 acc[ROWS_PER_WAVE];
  #pragma unroll
  for (int r = 0; r < ROWS_PER_WAVE; ++r) acc[r] = make_float4(0.f, 0.f, 0.f, 0.f);
  const float* wtbase = Wt + ((size_t)h * 64) * 128 + 4 * l;
  #pragma unroll 4
  for (int i = 0; i < 64; ++i) {
    float4 wv = *(const float4*)(wtbase + (size_t)i * 128);
    #pragma unroll
    for (int r = 0; r < ROWS_PER_WAVE; ++r) {
      float ev = s_emb[wid][r][h * 64 + i];  // 2-addr broadcast: free
      acc[r].x += wv.x * ev; acc[r].y += wv.y * ev;
      acc[r].z += wv.z * ev; acc[r].w += wv.w * ev;
    }
  }
  // combine the two halves: lane l and l+32 both end with the full sums
  #pragma unroll
  for (int r = 0; r < ROWS_PER_WAVE; ++r) {
    acc[r].x += __shfl_xor(acc[r].x, 32, 64);
    acc[r].y += __shfl_xor(acc[r].y, 32, 64);
    acc[r].z += __shfl_xor(acc[r].z, 32, 64);
    acc[r].w += __shfl_xor(acc[r].w, 32, 64);
  }

  // ---- + bias, ||leader||; leader stays in registers (ld[r]) ----
  const float4 bv = ((const float4*)bias)[l];
  float4 ld[ROWS_PER_WAVE];
  float  na[ROWS_PER_WAVE];
  #pragma unroll
  for (int r = 0; r < ROWS_PER_WAVE; ++r) {
    ld[r].x = acc[r].x + bv.x; ld[r].y = acc[r].y + bv.y;
    ld[r].z = acc[r].z + bv.z; ld[r].w = acc[r].w + bv.w;
    float p = ld[r].x * ld[r].x + ld[r].y * ld[r].y +
              ld[r].z * ld[r].z + ld[r].w * ld[r].w;
    #pragma unroll
    for (int m = 1; m <= 16; m <<= 1) p += __shfl_xor(p, m, 64);  // halves dup
    na[r] = sqrtf(p);
  }

  // ---- cosine logits: 2 words/slot (one per half), 4 rows interleaved
  //      (4 loads in flight + 8 parallel shuffle chains per slot) ----
  for (int s = 0; s < NSLOT; ++s) {
    float4 cur[ROWS_PER_WAVE];
    #pragma unroll
    for (int r = 0; r < ROWS_PER_WAVE; ++r) cur[r] = t[s & 1][r];
    if (s + 2 < NSLOT) {
      #pragma unroll
      for (int r = 0; r < ROWS_PER_WAVE; ++r)
        t[s & 1][r] = txt4[r][(size_t)(2 * (s + 2) + h) * 32 + l];
    }
    float dt[ROWS_PER_WAVE], nb[ROWS_PER_WAVE];
    #pragma unroll
    for (int r = 0; r < ROWS_PER_WAVE; ++r) {
      dt[r] = cur[r].x * ld[r].x + cur[r].y * ld[r].y +
              cur[r].z * ld[r].z + cur[r].w * ld[r].w;
      nb[r] = cur[r].x * cur[r].x + cur[r].y * cur[r].y +
              cur[r].z * cur[r].z + cur[r].w * cur[r].w;
    }
    #pragma unroll
    for (int m = 1; m <= 16; m <<= 1) {
      #pragma unroll
      for (int r = 0; r < ROWS_PER_WAVE; ++r) {
        dt[r] += __shfl_xor(dt[r], m, 64);
        nb[r] += __shfl_xor(nb[r], m, 64);
      }
    }
    if (l == 0) {
      #pragma unroll
      for (int r = 0; r < ROWS_PER_WAVE; ++r)
        s_logit[wid][r][2 * s + h] = dt[r] / fmaxf(na[r] * sqrtf(nb[r]), 1e-8f);
    }
  }
  // same-wave LDS write->read again: no barrier needed.

  // ---- softmax over 50 words, 4 rows interleaved ----
  float lg[ROWS_PER_WAVE], mx[ROWS_PER_WAVE];
  #pragma unroll
  for (int r = 0; r < ROWS_PER_WAVE; ++r) {
    lg[r] = (lane < NUM_WORDS) ? s_logit[wid][r][lane] : -INFINITY;
    mx[r] = lg[r];
  }
  #pragma unroll
  for (int m = 1; m < 64; m <<= 1)
    #pragma unroll
    for (int r = 0; r < ROWS_PER_WAVE; ++r)
      mx[r] = fmaxf(mx[r], __shfl_xor(mx[r], m, 64));
  float ex[ROWS_PER_WAVE], sum[ROWS_PER_WAVE];
  #pragma unroll
  for (int r = 0; r < ROWS_PER_WAVE; ++r) {
    ex[r]  = (lane < NUM_WORDS) ? __expf(lg[r] - mx[r]) : 0.f;
    sum[r] = ex[r];
  }
  #pragma unroll
  for (int m = 1; m < 64; m <<= 1)
    #pragma unroll
    for (int r = 0; r < ROWS_PER_WAVE; ++r)
      sum[r] += __shfl_xor(sum[r], m, 64);
  if (lane < NUM_WORDS) {
    #pragma unroll
    for (int r = 0; r < ROWS_PER_WAVE; ++r)
      out[(size_t)(b0 + r) * NUM_WORDS + lane] = ex[r] / sum[r];
  }
}

extern "C" void kernel_launch(void* const* d_in, const int* in_sizes, int n_in,
                              void* d_out, int out_size, void* d_ws, size_t ws_size,
                              hipStream_t stream) {
  const float* img  = (const float*)d_in[0];  // x_img_dense [B,64,128]
  const float* txt  = (const float*)d_in[1];  // x_txt_dense [B,50,128]
  const float* y    = (const float*)d_in[2];  // y_what_card_leader_choose [B,64]
  const float* W    = (const float*)d_in[3];  // W_img1 [128,128]
  const float* bias = (const float*)d_in[4];  // b_img1 [128]
  float* out = (float*)d_out;                 // [B,50] float32
  float* Wt  = (float*)d_ws;                  // 64 KB transposed weights

  transpose_W<<<64, 256, 0, stream>>>(W, Wt);
  imaginarium_kernel<<<B_TOT / ROWS_PER_BLOCK, 256, 0, stream>>>(
      img, txt, y, Wt, bias, out);
}